// Round 2
// baseline (293.229 us; speedup 1.0000x reference)
//
#include <hip/hip_runtime.h>

// Capsule routing layer, MI355X.  B=2048, I=64, O=32, DI=DO=16, 3 iters.
// transpose_x: x (B,DI,I) -> xt (B,I,DI) so A-phase loads are 4x dwordx4.
// routing_kernel: block = 256 thr (4 waves), one o, NB=8 b's, 32 KB LDS
//   (5 blocks/CU = 20 waves/CU).
// A-phase: lane=i, wave w owns d in [4w,4w+4); W+noise in regs (64 VGPR).
// B-phase: thread = (half h, row r=bp*16+d); owns i in [h*32,h*32+32);
//   p[32] in regs, softmax serial per lane, halves combined via LDS partials
//   aliased onto the dead priors buffer. No max-subtraction (|logit|<~75 in
//   log2 units, fp32 exp cannot overflow).

#define NB 8
#define THREADS 256

__global__ __launch_bounds__(256) void transpose_x(
    const float* __restrict__ x, float* __restrict__ xt)
{
    __shared__ float t[16 * 65];            // [e][i], padded
    const int b   = blockIdx.x;
    const int tid = threadIdx.x;
    #pragma unroll
    for (int k = 0; k < 4; ++k) {
        const int idx = k * 256 + tid;      // e = idx>>6, i = idx&63
        t[(idx >> 6) * 65 + (idx & 63)] = x[b * 1024 + idx];
    }
    __syncthreads();
    const int i = tid >> 2, e4 = tid & 3;
    float4 v;
    v.x = t[(e4 * 4 + 0) * 65 + i];
    v.y = t[(e4 * 4 + 1) * 65 + i];
    v.z = t[(e4 * 4 + 2) * 65 + i];
    v.w = t[(e4 * 4 + 3) * 65 + i];
    *reinterpret_cast<float4*>(xt + b * 1024 + i * 16 + e4 * 4) = v;
}

template <bool XT>
__global__ __launch_bounds__(THREADS, 5) void routing_kernel(
    const float* __restrict__ x,    // XT ? (B,I,DI) : (B,DI,I)
    const float* __restrict__ rw,   // (O, I, DO, DI) = (32,64,16,16)
    const float* __restrict__ ns,   // same
    float* __restrict__ out)        // (1, O, B, DO)
{
    __shared__ float p_lds[8192];   // 32 KB: [row=bb*16+d][64 i, swizzled]

    const int tid  = threadIdx.x;
    const int w    = tid >> 6;      // wave 0..3
    const int lane = tid & 63;

    const int o  = blockIdx.x & 31;
    const int bc = blockIdx.x >> 5; // b chunk 0..255

    // ---- W+noise fragment: lane=i, d = 4w+dp ----
    float wq[4][4][4];              // [dp][eq][k] -> W[o, lane, 4w+dp, 4eq+k]
    {
        const int base = (o * 64 + lane) * 256 + (w * 4) * 16;
        #pragma unroll
        for (int dp = 0; dp < 4; ++dp) {
            #pragma unroll
            for (int eq = 0; eq < 4; ++eq) {
                const int idx = base + dp * 16 + eq * 4;
                const float4 a = *reinterpret_cast<const float4*>(rw + idx);
                const float4 n = *reinterpret_cast<const float4*>(ns + idx);
                wq[dp][eq][0] = a.x + n.x;
                wq[dp][eq][1] = a.y + n.y;
                wq[dp][eq][2] = a.z + n.z;
                wq[dp][eq][3] = a.w + n.w;
            }
        }
    }

    // ---- A phase: priors -> LDS ----
    for (int bb = 0; bb < NB; ++bb) {
        const int b = bc * NB + bb;
        float xv[16];
        if (XT) {
            const float4* xb = reinterpret_cast<const float4*>(x + b * 1024 + lane * 16);
            #pragma unroll
            for (int q = 0; q < 4; ++q) {
                const float4 v = xb[q];
                xv[4*q+0] = v.x; xv[4*q+1] = v.y; xv[4*q+2] = v.z; xv[4*q+3] = v.w;
            }
        } else {
            const float* xb = x + b * 1024 + lane;
            #pragma unroll
            for (int e = 0; e < 16; ++e) xv[e] = xb[e * 64];
        }

        #pragma unroll
        for (int dp = 0; dp < 4; ++dp) {
            float acc = 0.f;
            #pragma unroll
            for (int eq = 0; eq < 4; ++eq) {
                acc = fmaf(wq[dp][eq][0], xv[4*eq+0], acc);
                acc = fmaf(wq[dp][eq][1], xv[4*eq+1], acc);
                acc = fmaf(wq[dp][eq][2], xv[4*eq+2], acc);
                acc = fmaf(wq[dp][eq][3], xv[4*eq+3], acc);
            }
            const int d   = w * 4 + dp;
            const int row = bb * 16 + d;
            const int fi  = row * 64 + ((((lane >> 2) ^ (d & 7)) << 2) | (lane & 3));
            p_lds[fi] = acc;
        }
    }

    __syncthreads();                                    // #1: priors ready

    // ---- B phase: thread = (h, r); owns i in [h*32, h*32+32) ----
    const int h  = tid >> 7;        // half 0/1
    const int r  = tid & 127;       // row = bp*16 + d
    const int bp = r >> 4;
    const int d  = r & 15;

    float p[32];
    {
        const float4* pl = reinterpret_cast<const float4*>(p_lds) + r * 16 + h * 8;
        #pragma unroll
        for (int g = 0; g < 8; ++g) {
            const float4 v = pl[g ^ (d & 7)];           // contents: i = h*32+4g..+3
            p[4*g+0] = v.x; p[4*g+1] = v.y; p[4*g+2] = v.z; p[4*g+3] = v.w;
        }
    }

    __syncthreads();                                    // #2: p consumed, LDS reusable

    // ---- iter 0: softmax(0) uniform -> mean over i ----
    float part = 0.f;
    #pragma unroll
    for (int i = 0; i < 32; ++i) part += p[i];
    p_lds[h * 128 + r] = part;
    __syncthreads();                                    // #3
    float s = (part + p_lds[(1 ^ h) * 128 + r]) * (1.0f / 64.0f);

    float sn = s * s;               // squash norm over d (16-lane groups)
    sn += __shfl_xor(sn, 1);
    sn += __shfl_xor(sn, 2);
    sn += __shfl_xor(sn, 4);
    sn += __shfl_xor(sn, 8);
    float factor = sqrtf(sn) / (1.0f + sn);
    float Vsum = s * factor;        // logits[i,d] = p[i,d] * Vsum[d]

    // ---- iters 1,2 ----
    #pragma unroll
    for (int it = 0; it < 2; ++it) {
        const float c = Vsum * 1.44269504089f;          // log2(e)
        float denom = 0.f, num = 0.f;
        #pragma unroll
        for (int i = 0; i < 32; ++i) {
            const float E = exp2f(p[i] * c);            // no max-sub: cannot overflow
            denom += E;
            num = fmaf(E, p[i], num);
        }
        float2* ex = reinterpret_cast<float2*>(p_lds + 256 + it * 512);
        ex[h * 128 + r] = make_float2(denom, num);
        __syncthreads();                                // #4 / #5
        const float2 oth = ex[(1 ^ h) * 128 + r];
        s = (num + oth.y) / (denom + oth.x);
        sn = s * s;
        sn += __shfl_xor(sn, 1);
        sn += __shfl_xor(sn, 2);
        sn += __shfl_xor(sn, 4);
        sn += __shfl_xor(sn, 8);
        factor = sqrtf(sn) / (1.0f + sn);
        Vsum += s * factor;
    }

    if (h == 0) {
        const int b = bc * NB + bp;
        out[(o * 2048 + b) * 16 + d] = s * factor;      // (1,O,B,DO)
    }
}

extern "C" void kernel_launch(void* const* d_in, const int* in_sizes, int n_in,
                              void* d_out, int out_size, void* d_ws, size_t ws_size,
                              hipStream_t stream) {
    const float* x  = (const float*)d_in[0];
    const float* rw = (const float*)d_in[1];
    const float* ns = (const float*)d_in[2];
    float* out = (float*)d_out;
    (void)in_sizes; (void)n_in; (void)out_size;

    const int grid = (2048 / NB) * 32;                  // blockIdx = bc*32 + o
    const size_t xt_bytes = 2048u * 1024u * sizeof(float);

    if (ws_size >= xt_bytes) {
        float* xt = (float*)d_ws;
        transpose_x<<<2048, 256, 0, stream>>>(x, xt);
        routing_kernel<true><<<grid, THREADS, 0, stream>>>(xt, rw, ns, out);
    } else {
        routing_kernel<false><<<grid, THREADS, 0, stream>>>(x, rw, ns, out);
    }
}

// Round 3
// 205.190 us; speedup vs baseline: 1.4291x; 1.4291x over previous
//
#include <hip/hip_runtime.h>

// Capsule routing layer, MI355X.  B=2048, I=64, O=32, DI=DO=16, 3 iters.
// transpose_x: x (B,DI,I) -> xt (B,I,DI) so A-phase loads are 4x dwordx4.
// routing_kernel: block = 256 thr (4 waves), one o, NB=8 b's, 32 KB LDS.
//   NO min-wave forcing: round 2 showed __launch_bounds__(256,5) caps VGPR
//   at 48 -> wq spills to scratch -> 242 MB HBM fetch, 2x slower. Natural
//   VGPR (~60-110) + 32 KB LDS gives 4-5 blocks/CU by itself.
// Block order o-major: concurrent blocks share one o's W slice in L2.
// A-phase: lane=i, wave w owns d in [4w,4w+4); W+noise in regs.
// B-phase: thread = (half h, row r=bp*16+d); owns i in [h*32,h*32+32);
//   p[32] in regs, softmax serial per lane, halves combined via LDS partials
//   aliased onto the dead priors buffer. No max-subtraction (|logit*log2e|
//   < ~120 in log2 units, fp32 exp2 cannot overflow).

#define NB 8
#define THREADS 256

__global__ __launch_bounds__(256) void transpose_x(
    const float* __restrict__ x, float* __restrict__ xt)
{
    __shared__ float t[16 * 65];            // [e][i], padded
    const int b   = blockIdx.x;
    const int tid = threadIdx.x;
    #pragma unroll
    for (int k = 0; k < 4; ++k) {
        const int idx = k * 256 + tid;      // e = idx>>6, i = idx&63
        t[(idx >> 6) * 65 + (idx & 63)] = x[b * 1024 + idx];
    }
    __syncthreads();
    const int i = tid >> 2, e4 = tid & 3;
    float4 v;
    v.x = t[(e4 * 4 + 0) * 65 + i];
    v.y = t[(e4 * 4 + 1) * 65 + i];
    v.z = t[(e4 * 4 + 2) * 65 + i];
    v.w = t[(e4 * 4 + 3) * 65 + i];
    *reinterpret_cast<float4*>(xt + b * 1024 + i * 16 + e4 * 4) = v;
}

template <bool XT>
__global__ __launch_bounds__(THREADS) void routing_kernel(
    const float* __restrict__ x,    // XT ? (B,I,DI) : (B,DI,I)
    const float* __restrict__ rw,   // (O, I, DO, DI) = (32,64,16,16)
    const float* __restrict__ ns,   // same
    float* __restrict__ out)        // (1, O, B, DO)
{
    __shared__ float p_lds[8192];   // 32 KB: [row=bb*16+d][64 i, swizzled]

    const int tid  = threadIdx.x;
    const int w    = tid >> 6;      // wave 0..3
    const int lane = tid & 63;

    const int o  = blockIdx.x >> 8;   // o-major: concurrent blocks share W
    const int bc = blockIdx.x & 255;  // b chunk 0..255

    // ---- W+noise fragment: lane=i, d = 4w+dp ----
    float wq[4][4][4];              // [dp][eq][k] -> W[o, lane, 4w+dp, 4eq+k]
    {
        const int base = (o * 64 + lane) * 256 + (w * 4) * 16;
        #pragma unroll
        for (int dp = 0; dp < 4; ++dp) {
            #pragma unroll
            for (int eq = 0; eq < 4; ++eq) {
                const int idx = base + dp * 16 + eq * 4;
                const float4 a = *reinterpret_cast<const float4*>(rw + idx);
                const float4 n = *reinterpret_cast<const float4*>(ns + idx);
                wq[dp][eq][0] = a.x + n.x;
                wq[dp][eq][1] = a.y + n.y;
                wq[dp][eq][2] = a.z + n.z;
                wq[dp][eq][3] = a.w + n.w;
            }
        }
    }

    // ---- A phase: priors -> LDS ----
    for (int bb = 0; bb < NB; ++bb) {
        const int b = bc * NB + bb;
        float xv[16];
        if (XT) {
            const float4* xb = reinterpret_cast<const float4*>(x + b * 1024 + lane * 16);
            #pragma unroll
            for (int q = 0; q < 4; ++q) {
                const float4 v = xb[q];
                xv[4*q+0] = v.x; xv[4*q+1] = v.y; xv[4*q+2] = v.z; xv[4*q+3] = v.w;
            }
        } else {
            const float* xb = x + b * 1024 + lane;
            #pragma unroll
            for (int e = 0; e < 16; ++e) xv[e] = xb[e * 64];
        }

        #pragma unroll
        for (int dp = 0; dp < 4; ++dp) {
            float acc = 0.f;
            #pragma unroll
            for (int eq = 0; eq < 4; ++eq) {
                acc = fmaf(wq[dp][eq][0], xv[4*eq+0], acc);
                acc = fmaf(wq[dp][eq][1], xv[4*eq+1], acc);
                acc = fmaf(wq[dp][eq][2], xv[4*eq+2], acc);
                acc = fmaf(wq[dp][eq][3], xv[4*eq+3], acc);
            }
            const int d   = w * 4 + dp;
            const int row = bb * 16 + d;
            const int fi  = row * 64 + ((((lane >> 2) ^ (d & 7)) << 2) | (lane & 3));
            p_lds[fi] = acc;
        }
    }

    __syncthreads();                                    // #1: priors ready

    // ---- B phase: thread = (h, r); owns i in [h*32, h*32+32) ----
    const int h  = tid >> 7;        // half 0/1
    const int r  = tid & 127;       // row = bp*16 + d
    const int bp = r >> 4;
    const int d  = r & 15;

    float p[32];
    {
        const float4* pl = reinterpret_cast<const float4*>(p_lds) + r * 16 + h * 8;
        #pragma unroll
        for (int g = 0; g < 8; ++g) {
            const float4 v = pl[g ^ (d & 7)];           // contents: i = h*32+4g..+3
            p[4*g+0] = v.x; p[4*g+1] = v.y; p[4*g+2] = v.z; p[4*g+3] = v.w;
        }
    }

    __syncthreads();                                    // #2: p consumed, LDS reusable

    // ---- iter 0: softmax(0) uniform -> mean over i ----
    float part = 0.f;
    #pragma unroll
    for (int i = 0; i < 32; ++i) part += p[i];
    p_lds[h * 128 + r] = part;
    __syncthreads();                                    // #3
    float s = (part + p_lds[(1 ^ h) * 128 + r]) * (1.0f / 64.0f);

    float sn = s * s;               // squash norm over d (16-lane groups)
    sn += __shfl_xor(sn, 1);
    sn += __shfl_xor(sn, 2);
    sn += __shfl_xor(sn, 4);
    sn += __shfl_xor(sn, 8);
    float factor = sqrtf(sn) / (1.0f + sn);
    float Vsum = s * factor;        // logits[i,d] = p[i,d] * Vsum[d]

    // ---- iters 1,2 ----
    #pragma unroll
    for (int it = 0; it < 2; ++it) {
        const float c = Vsum * 1.44269504089f;          // log2(e)
        float denom = 0.f, num = 0.f;
        #pragma unroll
        for (int i = 0; i < 32; ++i) {
            const float E = exp2f(p[i] * c);            // no max-sub: cannot overflow
            denom += E;
            num = fmaf(E, p[i], num);
        }
        float2* ex = reinterpret_cast<float2*>(p_lds + 256 + it * 512);
        ex[h * 128 + r] = make_float2(denom, num);
        __syncthreads();                                // #4 / #5
        const float2 oth = ex[(1 ^ h) * 128 + r];
        s = (num + oth.y) / (denom + oth.x);
        sn = s * s;
        sn += __shfl_xor(sn, 1);
        sn += __shfl_xor(sn, 2);
        sn += __shfl_xor(sn, 4);
        sn += __shfl_xor(sn, 8);
        factor = sqrtf(sn) / (1.0f + sn);
        Vsum += s * factor;
    }

    if (h == 0) {
        const int b = bc * NB + bp;
        out[(o * 2048 + b) * 16 + d] = s * factor;      // (1,O,B,DO)
    }
}

extern "C" void kernel_launch(void* const* d_in, const int* in_sizes, int n_in,
                              void* d_out, int out_size, void* d_ws, size_t ws_size,
                              hipStream_t stream) {
    const float* x  = (const float*)d_in[0];
    const float* rw = (const float*)d_in[1];
    const float* ns = (const float*)d_in[2];
    float* out = (float*)d_out;
    (void)in_sizes; (void)n_in; (void)out_size;

    const int grid = 32 * 256;                          // blockIdx = o*256 + bc
    const size_t xt_bytes = 2048u * 1024u * sizeof(float);

    if (ws_size >= xt_bytes) {
        float* xt = (float*)d_ws;
        transpose_x<<<2048, 256, 0, stream>>>(x, xt);
        routing_kernel<true><<<grid, THREADS, 0, stream>>>(xt, rw, ns, out);
    } else {
        routing_kernel<false><<<grid, THREADS, 0, stream>>>(x, rw, ns, out);
    }
}

// Round 4
// 120.116 us; speedup vs baseline: 2.4412x; 1.7083x over previous
//
#include <hip/hip_runtime.h>

// Capsule routing, MI355X. B=2048, I=64, O=32, DI=DO=16, 3 iters.
// One kernel. Block = 256 thr (4 waves), one o, NB=16 b's in TWO sub-rounds
// of 8 over one 32 KB LDS priors buffer (W-load amortized over 16 b's, LDS
// still allows ~5 blocks/CU).
// A-phase: lane=i, wave w owns d in [4w,4w+4); W+noise in regs (64 VGPR).
// B-phase: thread=(bp=tid>>5, h=(tid>>4)&1, d=tid&15); owns i in
//   [h*32,h*32+32); halves combine via __shfl_xor(...,16) (same wave, no
//   barrier, no LDS exchange). Squash-norm over d via shfl_xor 1,2,4,8.
// Schedule: A0 | bar | read0 | bar | A1 + compute0 (x-loads hide under
//   softmax; wq dead after A1) | bar | read1 | compute1.
// exp2 via __builtin_amdgcn_exp2f (|arg| <= ~115 < 127, no overflow: |Vsum|<3,
//   |p|<~26). Reciprocals via v_rcp (rel err ~1e-7, tolerance slack 8x).

#define THREADS 256

__global__ __launch_bounds__(THREADS) void routing_kernel(
    const float* __restrict__ x,    // (B, DI, I) = (2048,16,64)
    const float* __restrict__ rw,   // (O, I, DO, DI) = (32,64,16,16)
    const float* __restrict__ ns,   // same
    float* __restrict__ out)        // (1, O, B, DO)
{
    __shared__ float p_lds[8192];   // 32 KB: [row=bb*16+d][64 i, swizzled]

    const int tid  = threadIdx.x;
    const int w    = tid >> 6;      // wave 0..3
    const int lane = tid & 63;      // = i in A-phase

    const int o  = blockIdx.x >> 7;   // o-major: 128 consecutive blocks share W
    const int bc = blockIdx.x & 127;  // 16-b chunk

    // ---- W+noise fragment: lane=i, d = 4w+dp ----
    float wq[4][16];                // [dp][e] -> W[o, lane, 4w+dp, e]
    {
        const int base = (o * 64 + lane) * 256 + (w * 4) * 16;
        #pragma unroll
        for (int dp = 0; dp < 4; ++dp) {
            #pragma unroll
            for (int eq = 0; eq < 4; ++eq) {
                const int idx = base + dp * 16 + eq * 4;
                const float4 a = *reinterpret_cast<const float4*>(rw + idx);
                const float4 n = *reinterpret_cast<const float4*>(ns + idx);
                wq[dp][4*eq+0] = a.x + n.x;
                wq[dp][4*eq+1] = a.y + n.y;
                wq[dp][4*eq+2] = a.z + n.z;
                wq[dp][4*eq+3] = a.w + n.w;
            }
        }
    }

    // B-phase thread mapping
    const int bpB = tid >> 5;        // 0..7 : b within sub-round
    const int hB  = (tid >> 4) & 1;  // i-half
    const int dB  = tid & 15;
    const int swz = dB & 7;

    // ---- A-phase helper (8 b's -> LDS) ----
    auto aphase = [&](int b0) {
        #pragma unroll
        for (int bb = 0; bb < 8; ++bb) {
            const float* xb = x + (b0 + bb) * 1024 + lane;
            float xv[16];
            #pragma unroll
            for (int e = 0; e < 16; ++e) xv[e] = xb[e * 64];  // coalesced
            #pragma unroll
            for (int dp = 0; dp < 4; ++dp) {
                float acc = 0.f;
                #pragma unroll
                for (int e = 0; e < 16; ++e) acc = fmaf(wq[dp][e], xv[e], acc);
                const int d  = w * 4 + dp;
                const int fi = (bb * 16 + d) * 64
                             + ((((lane >> 2) ^ (d & 7)) << 2) | (lane & 3));
                p_lds[fi] = acc;    // all 64 lanes -> one 64-word row, 2-way max
            }
        }
    };

    auto bread = [&](float* p) {
        const float4* pl = reinterpret_cast<const float4*>(p_lds)
                         + (bpB * 16 + dB) * 16 + hB * 8;
        #pragma unroll
        for (int g = 0; g < 8; ++g) {
            const float4 v = pl[g ^ swz];    // contents: i = hB*32 + 4g .. +3
            p[4*g+0] = v.x; p[4*g+1] = v.y; p[4*g+2] = v.z; p[4*g+3] = v.w;
        }
    };

    auto bcompute = [&](const float* p, int b0) {
        float part = 0.f;
        #pragma unroll
        for (int i = 0; i < 32; ++i) part += p[i];
        float s = (part + __shfl_xor(part, 16)) * (1.0f / 64.0f);

        float sn = s * s;
        sn += __shfl_xor(sn, 1); sn += __shfl_xor(sn, 2);
        sn += __shfl_xor(sn, 4); sn += __shfl_xor(sn, 8);
        float factor = sqrtf(sn) * __builtin_amdgcn_rcpf(1.0f + sn);
        float Vsum = s * factor;

        #pragma unroll
        for (int it = 0; it < 2; ++it) {
            const float c = Vsum * 1.44269504089f;   // log2(e)
            float den = 0.f, num = 0.f;
            #pragma unroll
            for (int i = 0; i < 32; ++i) {
                const float E = __builtin_amdgcn_exp2f(p[i] * c);
                den += E;
                num = fmaf(E, p[i], num);
            }
            den += __shfl_xor(den, 16);
            num += __shfl_xor(num, 16);
            s = num * __builtin_amdgcn_rcpf(den);
            sn = s * s;
            sn += __shfl_xor(sn, 1); sn += __shfl_xor(sn, 2);
            sn += __shfl_xor(sn, 4); sn += __shfl_xor(sn, 8);
            factor = sqrtf(sn) * __builtin_amdgcn_rcpf(1.0f + sn);
            Vsum += s * factor;
        }

        if (hB == 0)
            out[(o * 2048 + b0 + bpB) * 16 + dB] = s * factor;
    };

    const int bbase = bc * 16;
    float p0[32], p1[32];

    aphase(bbase);                  // sub-round 0 priors
    __syncthreads();                // LDS ready
    bread(p0);
    __syncthreads();                // all reads done; LDS reusable
    aphase(bbase + 8);              // sub-round 1 (loads issue early)...
    bcompute(p0, bbase);            // ...softmax 0 overlaps (wq dead after A1)
    __syncthreads();                // LDS ready
    bread(p1);
    bcompute(p1, bbase + 8);
}

extern "C" void kernel_launch(void* const* d_in, const int* in_sizes, int n_in,
                              void* d_out, int out_size, void* d_ws, size_t ws_size,
                              hipStream_t stream) {
    const float* x  = (const float*)d_in[0];
    const float* rw = (const float*)d_in[1];
    const float* ns = (const float*)d_in[2];
    float* out = (float*)d_out;
    (void)d_ws; (void)ws_size; (void)in_sizes; (void)n_in; (void)out_size;

    const int grid = 32 * 128;      // blockIdx = o*128 + bc
    routing_kernel<<<grid, THREADS, 0, stream>>>(x, rw, ns, out);
}